// Round 6
// baseline (1047.239 us; speedup 1.0000x reference)
//
#include <hip/hip_runtime.h>
#include <cstddef>

// FAN_39273180955145 — round 16. r15 post-mortem: un-merging phases removed
// only ~30MB of the ~250MB spill traffic (WRITE 385->356, FETCH 103->72) ->
// the merge was NOT the spill source. Prime suspect common to r14/r15 but
// absent in spill-free r10: the bqr[8] hoist = 32 arch VGPRs pinned across
// the whole mt loop (exp temps + frag_from + PV operands = the arch-pressure
// peak). ~220MB excess writes == ~3 values re-spilled per mt iteration.
// Fix: revert scores to IN-LOOP bq loads (2 extra ds_read_b128 per kc2 iter,
// cheap), keep everything else from r15:
//  * Phase A/B dual-row chains (ka0/ka1, va0/va1), 96-accum peak.
//  * even/odd score chains sae/sao (accum-only, +16).
//  * operand-swapped packed-b64 vt stores, setprio, launch_bounds(512,2).
// Math identical to r8/r10 (passed, absmax 9.8e-4): S[s,t]=sum_f h[s,f]kh[t,f]
// +c_t, kh[t,f]=sum_e M'[f,e]h[t,e]; analytic 2-value log-kernel; fixed-max
// softmax p=exp(s-8); dtype detector; h in LDS; 1 block = 1 batch.

typedef unsigned short u16;
typedef unsigned int u32;
typedef short short8 __attribute__((ext_vector_type(8)));
typedef u32 u32x2 __attribute__((ext_vector_type(2)));
typedef float floatx16 __attribute__((ext_vector_type(16)));

__device__ __forceinline__ float b2f(u16 u){ return __uint_as_float(((u32)u) << 16); }
__device__ __forceinline__ u16 f2b(float f){
  u32 u = __float_as_uint(f);
  return (u16)((u + 0x7fffu + ((u >> 16) & 1u)) >> 16);
}
// flagged input load: f32 ? fp32 : bf16; non-finite -> 0
__device__ __forceinline__ float ldf(const u16* p, size_t i, int f32){
  float v = f32 ? ((const float*)p)[i] : b2f(p[i]);
  return __builtin_isfinite(v) ? v : 0.f;
}
__device__ __forceinline__ u32 pk2(float a, float b){
  return ((u32)f2b(b) << 16) | (u32)f2b(a);
}
// [rows][128 bf16] LDS region, 256B rows, 16B-chunk xor swizzle (2-way max = free)
__device__ __forceinline__ int swz(int row, int ch){ return (row << 8) | ((ch ^ (row & 15)) << 4); }
__device__ __forceinline__ floatx16 fz(){
  floatx16 z;
#pragma unroll
  for (int i = 0; i < 16; ++i) z[i] = 0.f;
  return z;
}
__device__ __forceinline__ floatx16 MF(short8 a, short8 b, floatx16 c){
  return __builtin_amdgcn_mfma_f32_32x32x16_bf16(a, b, c, 0, 0, 0);
}
// C-layout 32x32 tile (by value) -> k-chunk A-fragment via xor-32 exchange (r4-verified).
__device__ __forceinline__ short8 frag_from(floatx16 cv, int half, int q5){
  int r0 = half * 8;
  u32 e01 = pk2(cv[r0 + 0], cv[r0 + 1]);
  u32 e23 = pk2(cv[r0 + 2], cv[r0 + 3]);
  u32 o01 = pk2(cv[r0 + 4], cv[r0 + 5]);
  u32 o23 = pk2(cv[r0 + 6], cv[r0 + 7]);
  u32 s0 = q5 ? e01 : o01;
  u32 s1 = q5 ? e23 : o23;
  u32 r0v = __shfl_xor(s0, 32);
  u32 r1v = __shfl_xor(s1, 32);
  union { u32 u[4]; short8 v; } un;
  un.u[0] = q5 ? r0v : e01;
  un.u[1] = q5 ? r1v : e23;
  un.u[2] = q5 ? o01 : r0v;
  un.u[3] = q5 ? o23 : r1v;
  return un.v;
}

// ---------------- dtype detector (r4-verified) ----------------
__global__ __launch_bounds__(256) void k_detect(const u16* x, int* dflag){
  __shared__ int red[256];
  int t = threadIdx.x, cnt = 0;
  for (int i = t; i < 4096; i += 256){
    u16 v = x[2 * i];
    int e = (v >> 7) & 0xFF;
    if (e == 0xFF || e >= 0x90 || (e > 0 && e <= 0x20)) ++cnt;
  }
  red[t] = cnt;
  __syncthreads();
  for (int off = 128; off > 0; off >>= 1){
    if (t < off) red[t] += red[t + off];
    __syncthreads();
  }
  if (t == 0) dflag[0] = (red[0] > 1000) ? 1 : 0;
}

// ---------------- prep kernels ----------------

// Mrow[r][c] = M'[r,c] (row-major, kh A-operand); vWT[d][e] = vW[e][d]; uv = u'.
__global__ __launch_bounds__(128) void k_prepw(const u16* qW, const u16* kW, const u16* vW,
                                               const u16* qb, u16* Mrow, u16* vWT, float* uv,
                                               const int* dflag){
  int fl = dflag[0];
  int i = blockIdx.x >> 7, f = blockIdx.x & 127, e = threadIdx.x;
  size_t qo = (size_t)(i * 128 + e) * 128;   // qW row e
  size_t ko = (size_t)(i * 128 + f) * 128;   // kW row f
  float m = 0.f;
  for (int d = 0; d < 128; ++d) m += ldf(qW, qo + d, fl) * ldf(kW, ko + d, fl);
  const float RS = 0.08838834764831845f;  // 1/sqrt(128)
  Mrow[(i * 128 + e) * 128 + f] = f2b(m * RS);                // M'[e,f] at [e][f]
  vWT[(i * 128 + f) * 128 + e] = f2b(ldf(vW, qo + f, fl));    // vWT[d][e] = vW[e][d]
  __shared__ float red[128];
  red[e] = ldf(kW, ko + e, fl) * ldf(qb, (size_t)i * 128 + e, fl);
  __syncthreads();
  for (int off = 64; off > 0; off >>= 1){
    if (e < off) red[e] += red[e + off];
    __syncthreads();
  }
  if (e == 0) uv[i * 128 + f] = red[0] * RS;
}

__global__ __launch_bounds__(256) void k_h1t(const u16* h1W, u16* h1WT, const int* dflag){
  int fl = dflag[0];
  __shared__ u16 tile[64][130];
  int k0 = blockIdx.x * 64, tid = threadIdx.x;
#pragma unroll 4
  for (int it = 0; it < 32; ++it){
    int r = it * 2 + (tid >> 7), c = tid & 127;
    tile[r][c] = f2b(ldf(h1W, (size_t)(k0 + r) * 128 + c, fl));
  }
  __syncthreads();
#pragma unroll 4
  for (int it = 0; it < 32; ++it){
    int idx = it * 256 + tid, n = idx >> 6, kk = idx & 63;
    h1WT[(size_t)n * 32896 + k0 + kk] = tile[kk][n];
  }
}

// -------- fused embed + 2 attention layers; h in LDS; one block = one batch --------

__global__ __launch_bounds__(512, 2) void k_fan(
    const u16* x, const u16* sW, const u16* sb, const u16* hW, const u16* hbe,
    const u16* Mrow, const float* uv, const u16* vWT, const u16* vb,
    const u16* lng, const u16* lnb,
    u16* hgq, u16* se, int qoff, const int* dflag){
  __shared__ alignas(16) u16 hL[32768];    // h   [256 s][128 f], swz, 64KB
  __shared__ alignas(16) u16 vt[16384];    // vT  [128 d][128 t], swz, 32KB
  __shared__ alignas(16) u16 khL[16384];   // kh  [128 t][128 f], swz, 32KB
  __shared__ float c_all[256];             // c_t, whole layer
  __shared__ float u_lds[128];             // u' for current layer
  int fl = dflag[0];
  int bl = blockIdx.x;
  int b = qoff + bl;
  int tid = threadIdx.x, w = tid >> 6, lane = tid & 63, l31 = lane & 31, q5 = lane >> 5;
  size_t xo = (size_t)b * 272;
  const float LKOFF = -20.72326584f;       // ln(1e-9); off-diag log-kernel value

  // scalar embedding (lanes 0..127)
  if (tid < 128){
    float acc = ldf(sb, tid, fl);
#pragma unroll
    for (int j = 0; j < 16; ++j) acc += ldf(x, xo + j, fl) * ldf(sW, (size_t)j * 128 + tid, fl);
    se[(size_t)b * 128 + tid] = f2b(acc);
  }
  // history embedding -> hL
#pragma unroll
  for (int it = 0; it < 8; ++it){
    int c = it * 512 + tid, s = c >> 4, ch = c & 15;
    float xv = ldf(x, xo + 16 + s, fl);
    short8 r;
#pragma unroll
    for (int j = 0; j < 8; ++j)
      r[j] = (short)f2b(xv * ldf(hW, ch * 8 + j, fl) + ldf(hbe, ch * 8 + j, fl));
    *(short8*)((char*)hL + swz(s, ch)) = r;
  }

#pragma unroll 1
  for (int li = 0; li < 2; ++li){
    const u16* Mri  = Mrow + li * 16384;
    const u16* vWTi = vWT + li * 16384;
    if (tid < 128) u_lds[tid] = uv[li * 128 + tid];
    __syncthreads();                 // hL (embed/prev epilogue) + u_lds visible

    // ---- c_all[t] = u'.h_t for all 256 rows; MFMA-operand access pattern (2-way, free)
    {
      int row = 32 * w + l31;
      float dot = 0.f;
#pragma unroll 2
      for (int kc = 0; kc < 8; ++kc){
        int ch = 2 * kc + q5;
        short8 hv = *(const short8*)((char*)hL + swz(row, ch));
#pragma unroll
        for (int j = 0; j < 8; ++j) dot += u_lds[ch * 8 + j] * b2f(hv[j]);
      }
      dot += __shfl_xor(dot, 32);
      if (q5 == 0) c_all[row] = dot;
    }

    float ls_tot = 0.f;
    floatx16 oacc[4];
#pragma unroll
    for (int nt = 0; nt < 4; ++nt) oacc[nt] = fz();
    int scol = 32 * w + l31;

#pragma unroll 1
    for (int tt = 0; tt < 2; ++tt){
      int t0 = tt * 128;
      __syncthreads();               // prior tile's khL/vt reads done; c_all visible
      int mtv = w & 3, ntv0 = (w >> 2) * 2;
      int r0 = t0 + 32 * ntv0 + l31, r1 = r0 + 32;
      // ---- Phase A: kh-tile, dual-row chains (ka0/ka1); accum peak oacc+32
      // kh[t][f] = sum_e M'[f,e] h[t,e]  (A=Mrow rows, B=h rows)
      {
        const u16* Ma = Mri + (32 * mtv + l31) * 128 + q5 * 8;
        floatx16 ka0 = fz(), ka1 = fz();
#pragma unroll 2
        for (int kc = 0; kc < 8; ++kc){
          short8 avM = *(const short8*)(Ma + kc * 16);
          short8 bh0 = *(const short8*)((char*)hL + swz(r0, 2 * kc + q5));
          short8 bh1 = *(const short8*)((char*)hL + swz(r1, 2 * kc + q5));
          ka0 = MF(avM, bh0, ka0);
          ka1 = MF(avM, bh1, ka1);
        }
        // kh stores: regs 4qd..4qd+3 -> frow = 32mtv + 8qd + 4q5 + (0..3): one 8B chunk
#pragma unroll
        for (int j = 0; j < 2; ++j){
          floatx16 ka = j ? ka1 : ka0;
          int tloc = 32 * (ntv0 + j) + l31;
#pragma unroll
          for (int qd = 0; qd < 4; ++qd){
            u32x2 pv;
            pv.x = pk2(ka[4 * qd + 0], ka[4 * qd + 1]);
            pv.y = pk2(ka[4 * qd + 2], ka[4 * qd + 3]);
            *(u32x2*)((char*)khL + swz(tloc, 4 * mtv + qd) + 8 * q5) = pv;
          }
        }
      }
      // ---- Phase B: v-tile, operand-swapped (D[t][d]), dual-row chains
      // v[t][d] = sum_e h[t,e] vW[e,d]  (A=h rows, B=vWT rows)
      {
        const u16* Va = vWTi + (32 * mtv + l31) * 128 + q5 * 8;
        float vbl = ldf(vb, (size_t)li * 128 + 32 * mtv + l31, fl);
        floatx16 va0 = fz(), va1 = fz();
#pragma unroll 2
        for (int kc = 0; kc < 8; ++kc){
          short8 avV = *(const short8*)(Va + kc * 16);
          short8 bh0 = *(const short8*)((char*)hL + swz(r0, 2 * kc + q5));
          short8 bh1 = *(const short8*)((char*)hL + swz(r1, 2 * kc + q5));
          va0 = MF(bh0, avV, va0);
          va1 = MF(bh1, avV, va1);
        }
        // v stores: lane -> d row, regs -> consecutive t; lane-local bias
#pragma unroll
        for (int j = 0; j < 2; ++j){
          floatx16 va = j ? va1 : va0;
#pragma unroll
          for (int qd = 0; qd < 4; ++qd){
            u32x2 pv;
            pv.x = pk2(va[4 * qd + 0] + vbl, va[4 * qd + 1] + vbl);
            pv.y = pk2(va[4 * qd + 2] + vbl, va[4 * qd + 3] + vbl);
            *(u32x2*)((char*)vt + swz(32 * mtv + l31, 4 * (ntv0 + j) + qd) + 8 * q5) = pv;
          }
        }
      }
      __syncthreads();               // khL, vt complete
      // ---- scores + exp + P@V, one 32-t subtile live at a time
      // bq loaded IN-LOOP (r16: no bqr hoist -> no 32-reg long-range hold)
#pragma unroll 1
      for (int mt = 0; mt < 4; ++mt){
        floatx16 sae = fz(), sao = fz();   // even/odd kc chains (halved dep path)
        __builtin_amdgcn_s_setprio(1);
#pragma unroll
        for (int kc2 = 0; kc2 < 4; ++kc2){
          short8 ak0 = *(const short8*)((char*)khL + swz(32 * mt + l31, 4 * kc2 + q5));
          short8 bq0 = *(const short8*)((char*)hL + swz(32 * w + l31, 4 * kc2 + q5));
          sae = MF(ak0, bq0, sae);
          short8 ak1 = *(const short8*)((char*)khL + swz(32 * mt + l31, 4 * kc2 + 2 + q5));
          short8 bq1 = *(const short8*)((char*)hL + swz(32 * w + l31, 4 * kc2 + 2 + q5));
          sao = MF(ak1, bq1, sao);
        }
        __builtin_amdgcn_s_setprio(0);
        floatx16 sa = sae + sao;
#pragma unroll
        for (int reg = 0; reg < 16; ++reg){
          int trl = 32 * mt + (reg & 3) + 8 * (reg >> 2) + 4 * q5;
          int tg = t0 + trl;
          float lk = (tg == scol) ? 0.f : LKOFF;
          float v = sa[reg] + c_all[tg] + lk;
          v = fminf(fmaxf(v, -50.f), 50.f);
          float p = __expf(v - 8.f);   // fixed max: softmax shift-invariant
          sa[reg] = p;
          ls_tot += p;
        }
        // pf frags computed BEFORE the bv loads so sa dies here (register diet)
        short8 pf0 = frag_from(sa, 0, q5);
        short8 pf1 = frag_from(sa, 1, q5);
        __builtin_amdgcn_s_setprio(1);
#pragma unroll
        for (int nt = 0; nt < 4; ++nt){
          short8 bv0 = *(const short8*)((char*)vt + swz(32 * nt + l31, 2 * (2 * mt + 0) + q5));
          oacc[nt] = MF(pf0, bv0, oacc[nt]);
          short8 bv1 = *(const short8*)((char*)vt + swz(32 * nt + l31, 2 * (2 * mt + 1) + q5));
          oacc[nt] = MF(pf1, bv1, oacc[nt]);
        }
        __builtin_amdgcn_s_setprio(0);
      }
    }
    __syncthreads();                   // all hL reads done before epilogue writes

    // ---- epilogue: /l, +residual, LayerNorm, write back to hL (own rows only)
    float l_run = ls_tot + __shfl_xor(ls_tot, 32);
    float linv = 1.f / l_run;
    float gv[4], bbv[4];
#pragma unroll
    for (int nt = 0; nt < 4; ++nt){
      gv[nt]  = ldf(lng, (size_t)li * 128 + 32 * nt + l31, fl);
      bbv[nt] = ldf(lnb, (size_t)li * 128 + 32 * nt + l31, fl);
    }
#pragma unroll
    for (int reg = 0; reg < 16; ++reg){
      int rr = (reg & 3) + 8 * (reg >> 2) + 4 * q5;
      int srow = 32 * w + rr;
      float lrv = __shfl(linv, rr);
      float s1 = 0.f, s2 = 0.f;
#pragma unroll
      for (int nt = 0; nt < 4; ++nt){
        int d = 32 * nt + l31;
        float res = b2f(*(const u16*)((char*)hL + swz(srow, d >> 3) + (d & 7) * 2));
        float v = oacc[nt][reg] * lrv + res;
        oacc[nt][reg] = v;
        s1 += v; s2 += v * v;
      }
#pragma unroll
      for (int off = 1; off < 32; off <<= 1){ s1 += __shfl_xor(s1, off); s2 += __shfl_xor(s2, off); }
      float mu = s1 * 0.0078125f;
      float rs = rsqrtf(fmaxf(s2 * 0.0078125f - mu * mu, 0.f) + 1e-5f);
#pragma unroll
      for (int nt = 0; nt < 4; ++nt){
        int d = 32 * nt + l31;
        float v = (oacc[nt][reg] - mu) * rs * gv[nt] + bbv[nt];
        *(u16*)((char*)hL + swz(srow, d >> 3) + (d & 7) * 2) = f2b(v);
      }
    }
    __syncthreads();                   // hL update visible before next layer / store
  }

  // final h -> global, coalesced 16B chunks
#pragma unroll
  for (int it = 0; it < 8; ++it){
    int c = it * 512 + tid, row = c >> 4, ch = c & 15;
    *(short8*)(hgq + (size_t)bl * 32768 + row * 128 + ch * 8) =
        *(const short8*)((char*)hL + swz(row, ch));
  }
}

// ---------------- MLP head ----------------

__global__ __launch_bounds__(256) void k_mlp1(const u16* se, const u16* hgq, const u16* h1WT,
                                              float* part, int qoff, int nb){
  int mb = blockIdx.x, ks = blockIdx.y;
  int tid = threadIdx.x, w = tid >> 6, lane = tid & 63, l31 = lane & 31, q5 = lane >> 5;
  int b0 = mb * 32;
  floatx16 acc = fz();
  const u16* brow = h1WT + (size_t)(32 * w + l31) * 32896;
  int br = b0 + l31;
  const u16* seb = se + (size_t)(qoff + br) * 128;
  const u16* hb = hgq + (size_t)br * 32768;
  for (int kk = 0; kk < 257; ++kk){
    int kbase = ks * 4112 + kk * 16;
    const u16* ap = (kbase < 128) ? (seb + kbase + q5 * 8) : (hb + (kbase - 128) + q5 * 8);
    short8 a = *(const short8*)ap;
    short8 bf = *(const short8*)(brow + kbase + q5 * 8);
    acc = MF(a, bf, acc);
  }
#pragma unroll
  for (int reg = 0; reg < 16; ++reg){
    int rr = (reg & 3) + 8 * (reg >> 2) + 4 * q5;
    part[(size_t)ks * nb * 128 + (size_t)(b0 + rr) * 128 + 32 * w + l31] = acc[reg];
  }
}

__global__ __launch_bounds__(256) void k_mlp1red(const float* part, const u16* h1b, float* z1q,
                                                 const int* dflag, int nb){
  int fl = dflag[0];
  int idx = blockIdx.x * 256 + threadIdx.x;    // 0..nb*128-1
  float s = ldf(h1b, idx & 127, fl);
  size_t stride = (size_t)nb * 128;
#pragma unroll
  for (int ks = 0; ks < 8; ++ks) s += part[(size_t)ks * stride + idx];
  z1q[idx] = fmaxf(s, 0.f);
}

__global__ __launch_bounds__(256) void k_mlp2(const float* z1, const u16* h2W, const u16* h2b,
                                              float* z2, const int* dflag){
  int fl = dflag[0];
  int idx = blockIdx.x * 256 + threadIdx.x;    // 0..131071
  int b = idx >> 6, j = idx & 63;
  float s = ldf(h2b, j, fl);
  const float* zr = z1 + (size_t)b * 128;
  for (int k = 0; k < 128; ++k) s += zr[k] * ldf(h2W, (size_t)k * 64 + j, fl);
  z2[idx] = fmaxf(s, 0.f);
}

__global__ __launch_bounds__(256) void k_mlp3(const float* z2, const u16* h3W, const u16* h3b,
                                              void* out, const int* dflag){
  int fl = dflag[0];
  int b = blockIdx.x * 256 + threadIdx.x;      // 0..2047
  float s = ldf(h3b, 0, fl);
  const float* zr = z2 + (size_t)b * 64;
#pragma unroll
  for (int j = 0; j < 64; ++j) s += zr[j] * ldf(h3W, j, fl);
  if (!__builtin_isfinite(s)) s = 0.f;
  if (fl) ((float*)out)[b] = s;
  else    ((u16*)out)[b] = f2b(s);
}

// ---------------- launch ----------------

extern "C" void kernel_launch(void* const* d_in, const int* in_sizes, int n_in,
                              void* d_out, int out_size, void* d_ws, size_t ws_size,
                              hipStream_t stream) {
  const u16* x   = (const u16*)d_in[0];
  const u16* sW  = (const u16*)d_in[1];
  const u16* sb  = (const u16*)d_in[2];
  const u16* hW  = (const u16*)d_in[3];
  const u16* hb  = (const u16*)d_in[4];
  const u16* qW  = (const u16*)d_in[5];
  const u16* qb  = (const u16*)d_in[6];
  const u16* kW  = (const u16*)d_in[7];
  // d_in[8] = kb : cancels in softmax, unused
  const u16* vW  = (const u16*)d_in[9];
  const u16* vb  = (const u16*)d_in[10];
  const u16* lng = (const u16*)d_in[11];
  const u16* lnb = (const u16*)d_in[12];
  const u16* h1W = (const u16*)d_in[13];
  const u16* h1b = (const u16*)d_in[14];
  const u16* h2W = (const u16*)d_in[15];
  const u16* h2b = (const u16*)d_in[16];
  const u16* h3W = (const u16*)d_in[17];
  const u16* h3b = (const u16*)d_in[18];

  // full-pass mode (r5-r8 ran this branch); quarter mode fallback.
  const int nb = (ws_size >= 153600000ull) ? 2048 : 512;
  const int nq = 2048 / nb;

  char* W = (char*)d_ws;
  size_t o = 0;
  u16*   hg    = (u16*)(W + o); o += (size_t)nb * 65536;   // nb*32768*2
  u16*   h1WT  = (u16*)(W + o); o += 8421376;
  u16*   se    = (u16*)(W + o); o += 524288;               // always full 2048x128 bf16
  u16*   Mrow  = (u16*)(W + o); o += 65536;
  u16*   vWT   = (u16*)(W + o); o += 65536;
  float* uv    = (float*)(W + o); o += 1024;
  float* part  = (float*)(W + o); o += (size_t)nb * 4096;  // 8 * nb*128 * 4B
  float* z1    = (float*)(W + o); o += 1048576;            // always full
  float* z2    = (float*)(W + o); o += 524288;
  int*   dflag = (int*)(W + o);

  k_detect<<<1, 256, 0, stream>>>(x, dflag);
  k_prepw<<<256, 128, 0, stream>>>(qW, kW, vW, qb, Mrow, vWT, uv, dflag);
  k_h1t<<<514, 256, 0, stream>>>(h1W, h1WT, dflag);

  for (int q = 0; q < nq; ++q){
    int qoff = q * nb;
    k_fan<<<nb, 512, 0, stream>>>(x, sW, sb, hW, hb, Mrow, uv, vWT, vb,
                                  lng, lnb, hg, se, qoff, dflag);
    k_mlp1<<<dim3(nb / 32, 8), 256, 0, stream>>>(se, hg, h1WT, part, qoff, nb);
    k_mlp1red<<<nb / 2, 256, 0, stream>>>(part, h1b, z1 + (size_t)qoff * 128, dflag, nb);
  }

  k_mlp2<<<512, 256, 0, stream>>>(z1, h2W, h2b, z2, dflag);
  k_mlp3<<<8, 256, 0, stream>>>(z2, h3W, h3b, d_out, dflag);
}